// Round 13
// baseline (178.452 us; speedup 1.0000x reference)
//
#include <hip/hip_runtime.h>
#include <hip/hip_bf16.h>
#include <math.h>

// ---------------------------------------------------------------------------
// GCN 2-layer forward. Pipeline (7 dispatches, ZERO global atomics):
//   1) wprep: W1^T -> bf16 hi/lo split
//   2) gemmhrank: GEMM1 (MFMA, 3-pass split bf16) || hrank (per-chunk,
//      per-dst-range LDS histogram -> chunkhist[c][d])
//   3) chpfxbsum: chunkhist -> in-place per-chunk prefix; count[d]; bsum
//   4) scan2 -> rd2 = {row_start, dinv}; seeds self-loop edata
//   5) fill: LDS re-rank (atomic-free globally) -> edata scatter
//   6) MEGA-B: agg1 (gather+bias+relu) -> h in LDS -> gemm2 -> h2 (bf16)
//   7) AGG2 (bf16 h2, 8 lanes/node) + bias + log_softmax fused
// ---------------------------------------------------------------------------

#define FIN 256
#define FH  128
#define FO  16
#define SCAN_CHUNK 1024
#define NCHUNK 32          // edge chunks
#define QPR_MAX 6272       // max nodes per dst-range (LDS histogram size)

typedef unsigned int uint;
typedef unsigned short ushort;
typedef __attribute__((ext_vector_type(8))) short bf16x8;
typedef __attribute__((ext_vector_type(4))) float f32x4;

static __device__ __forceinline__ ushort f2bf(float f) {
    __hip_bfloat16 b = __float2bfloat16(f);
    return *reinterpret_cast<ushort*>(&b);
}
static __device__ __forceinline__ float bf2f(ushort u) {
    return __uint_as_float(((uint)u) << 16);
}

// W-prep: W1[256][128] fp32 -> whT/wlT [128 cols][256 k] bf16 hi/lo split.
__global__ __launch_bounds__(256) void GCN_wprep_k(const float* __restrict__ W1,
                                                   ushort* __restrict__ whT,
                                                   ushort* __restrict__ wlT) {
    int i = blockIdx.x * 256 + threadIdx.x;   // 32768
    int k = i >> 7, c = i & 127;
    float w = W1[i];
    ushort hh = f2bf(w);
    ushort hl = f2bf(w - bf2f(hh));
    whT[c * 256 + k] = hh;
    wlT[c * 256 + k] = hl;
}

// GEMM1 tile params
#define G1_BR 64
#define G1_KC 32

// blocks [0,nGemm): GEMM1; blocks [nGemm, nGemm + NCHUNK*nRange): hrank.
// GEMM1: h1(bf16)[N][128] = x @ W1. 4 waves, tile 64x128, KC=32, 3-pass
// split-bf16 MFMA. LDS rows 64B, swizzle byte^=((r>>1)&3)<<4.
// hrank: block (c,r) LDS-histograms chunk c's edges with dst in range r.
__global__ __launch_bounds__(256, 4) void GCN_gemmhrank_k(
        const float* __restrict__ x, const ushort* __restrict__ whT,
        const ushort* __restrict__ wlT, ushort* __restrict__ h1,
        const int* __restrict__ edge, int* __restrict__ chunkhist,
        int N, int E, int nGemm, int nRange, int qpr, int ech) {
    __shared__ __align__(16) char smem[QPR_MAX * 4];   // 25088 B
    int tid = threadIdx.x;

    if ((int)blockIdx.x >= nGemm) {
        // ---- hrank path ----
        int bid = blockIdx.x - nGemm;
        int c = bid / nRange, r = bid % nRange;
        int* lhist = (int*)smem;
        for (int j = tid; j < qpr; j += 256) lhist[j] = 0;
        __syncthreads();
        int base = c * ech;
        int lim = base + ech; if (lim > E) lim = E;
        int r0 = r * qpr;
        for (int i = base + tid; i < lim; i += 256) {
            int d = edge[E + i];
            int dd = d - r0;
            if ((unsigned)dd < (unsigned)qpr) atomicAdd(&lhist[dd], 1);
        }
        __syncthreads();
        for (int j = tid; j < qpr; j += 256) {
            int d = r0 + j;
            if (d < N) chunkhist[(size_t)c * N + d] = lhist[j];
        }
        return;
    }

    // ---- gemm1 path ----
    ushort* xh_s = (ushort*)smem;              // 4 KiB
    ushort* xl_s = (ushort*)(smem + 4096);     // 4 KiB
    ushort* wh_s = (ushort*)(smem + 8192);     // 8 KiB
    ushort* wl_s = (ushort*)(smem + 16384);    // 8 KiB
    int row0 = blockIdx.x * G1_BR;
    int ln = tid & 63;
    int w  = tid >> 6;          // wave 0..3 -> col slab w*32
    int ln15 = ln & 15;
    int q16  = ln >> 4;         // k-slot 0..3

    f32x4 acc[4][2];
    #pragma unroll
    for (int mr = 0; mr < 4; mr++)
        #pragma unroll
        for (int nc = 0; nc < 2; nc++) acc[mr][nc] = (f32x4){0.f, 0.f, 0.f, 0.f};

    for (int kc = 0; kc < FIN; kc += G1_KC) {
        #pragma unroll
        for (int j = 0; j < 2; j++) {
            int u = tid + j * 256;
            int r = u >> 3, kq = u & 7;       // 8 float4 per row
            int gr = row0 + r;
            float4 v = make_float4(0.f, 0.f, 0.f, 0.f);
            if (gr < N) v = *(const float4*)&x[(size_t)gr * FIN + kc + kq * 4];
            ushort h0 = f2bf(v.x), h1v = f2bf(v.y), h2 = f2bf(v.z), h3 = f2bf(v.w);
            ushort l0 = f2bf(v.x - bf2f(h0));
            ushort l1 = f2bf(v.y - bf2f(h1v));
            ushort l2 = f2bf(v.z - bf2f(h2));
            ushort l3 = f2bf(v.w - bf2f(h3));
            uint2 hw, lw;
            hw.x = (uint)h0 | ((uint)h1v << 16);
            hw.y = (uint)h2 | ((uint)h3 << 16);
            lw.x = (uint)l0 | ((uint)l1 << 16);
            lw.y = (uint)l2 | ((uint)l3 << 16);
            int byte = (r * 64 + kq * 8) ^ (((r >> 1) & 3) << 4);
            *(uint2*)((char*)xh_s + byte) = hw;
            *(uint2*)((char*)xl_s + byte) = lw;
        }
        #pragma unroll
        for (int j = 0; j < 2; j++) {
            int u = tid + j * 256;
            int c = u >> 2, ku = u & 3;       // 4 x 16B per col
            uint4 vh = *(const uint4*)&whT[(size_t)c * 256 + kc + ku * 8];
            uint4 vl = *(const uint4*)&wlT[(size_t)c * 256 + kc + ku * 8];
            int byte = (c * 64 + ku * 16) ^ (((c >> 1) & 3) << 4);
            *(uint4*)((char*)wh_s + byte) = vh;
            *(uint4*)((char*)wl_s + byte) = vl;
        }
        __syncthreads();

        bf16x8 ah[4], al[4], bh[2], bl[2];
        #pragma unroll
        for (int mr = 0; mr < 4; mr++) {
            int r = mr * 16 + ln15;
            int byte = r * 64 + ((q16 * 16) ^ (((r >> 1) & 3) << 4));
            ah[mr] = *(const bf16x8*)((const char*)xh_s + byte);
            al[mr] = *(const bf16x8*)((const char*)xl_s + byte);
        }
        #pragma unroll
        for (int nc = 0; nc < 2; nc++) {
            int c = w * 32 + nc * 16 + ln15;
            int byte = c * 64 + ((q16 * 16) ^ (((c >> 1) & 3) << 4));
            bh[nc] = *(const bf16x8*)((const char*)wh_s + byte);
            bl[nc] = *(const bf16x8*)((const char*)wl_s + byte);
        }
        #pragma unroll
        for (int mr = 0; mr < 4; mr++)
            #pragma unroll
            for (int nc = 0; nc < 2; nc++) {
                acc[mr][nc] = __builtin_amdgcn_mfma_f32_16x16x32_bf16(
                    ah[mr], bh[nc], acc[mr][nc], 0, 0, 0);
                acc[mr][nc] = __builtin_amdgcn_mfma_f32_16x16x32_bf16(
                    al[mr], bh[nc], acc[mr][nc], 0, 0, 0);
                acc[mr][nc] = __builtin_amdgcn_mfma_f32_16x16x32_bf16(
                    ah[mr], bl[nc], acc[mr][nc], 0, 0, 0);
            }
        __syncthreads();
    }

    // epilogue: D layout col=lane&15, row=(lane>>4)*4+reg  [m89-verified]
    #pragma unroll
    for (int mr = 0; mr < 4; mr++) {
        #pragma unroll
        for (int nc = 0; nc < 2; nc++) {
            int cw = w * 32 + nc * 16 + ln15;
            #pragma unroll
            for (int j = 0; j < 4; j++) {
                int gr = row0 + mr * 16 + q16 * 4 + j;
                if (gr < N) h1[(size_t)gr * FH + cw] = f2bf(acc[mr][nc][j]);
            }
        }
    }
}

// chpfxbsum: chunkhist[c][d] -> in-place exclusive prefix over c;
// count[d] = total; bsum[blk] = sum(count+1) over the block's 1024 nodes.
__global__ __launch_bounds__(256) void GCN_chpfxbsum_k(int* __restrict__ chunkhist,
                                                       int* __restrict__ count,
                                                       int* __restrict__ bsum,
                                                       int N) {
    int tid = threadIdx.x;
    int d0 = blockIdx.x * SCAN_CHUNK + tid * 4;
    int local = 0;
    if (d0 + 3 < N) {
        int4 run = make_int4(0, 0, 0, 0);
        for (int c = 0; c < NCHUNK; c++) {
            int4* p = (int4*)&chunkhist[(size_t)c * N + d0];
            int4 v = *p;
            *p = run;
            run.x += v.x; run.y += v.y; run.z += v.z; run.w += v.w;
        }
        *(int4*)&count[d0] = run;
        local = run.x + run.y + run.z + run.w + 4;
    } else {
        for (int q = 0; q < 4; q++) {
            int d = d0 + q;
            if (d < N) {
                int run = 0;
                for (int c = 0; c < NCHUNK; c++) {
                    int* p = &chunkhist[(size_t)c * N + d];
                    int v = *p; *p = run; run += v;
                }
                count[d] = run;
                local += run + 1;
            }
        }
    }
    __shared__ int red[256];
    red[tid] = local;
    __syncthreads();
    for (int st = 128; st > 0; st >>= 1) {
        if (tid < st) red[tid] += red[tid + st];
        __syncthreads();
    }
    if (tid == 0) bsum[blockIdx.x] = red[0];
}

// scan2: rd2[v] = {row_start[v], bits(dinv[v])}; rd2[N].x = total;
// seeds self-loop entry edata[row_start[v]] = {v, dinv^2}.
__global__ __launch_bounds__(256) void GCN_scan2_k(const int* __restrict__ count,
                                                   const int* __restrict__ bsum,
                                                   int2* __restrict__ rd2,
                                                   int2* __restrict__ edata, int N) {
    int tid = threadIdx.x;
    int b = blockIdx.x;
    int i0 = b * SCAN_CHUNK + tid * 4;

    int v0 = 0, v1 = 0, v2 = 0, v3 = 0;
    if (i0 + 3 < N) {
        int4 c = *(const int4*)&count[i0];
        v0 = c.x + 1; v1 = c.y + 1; v2 = c.z + 1; v3 = c.w + 1;
    } else {
        if (i0 + 0 < N) v0 = count[i0 + 0] + 1;
        if (i0 + 1 < N) v1 = count[i0 + 1] + 1;
        if (i0 + 2 < N) v2 = count[i0 + 2] + 1;
        if (i0 + 3 < N) v3 = count[i0 + 3] + 1;
    }
    int lsum = v0 + v1 + v2 + v3;

    __shared__ int red[256];
    int offp = 0;
    for (int t = tid; t < b; t += 256) offp += bsum[t];
    red[tid] = offp;
    __syncthreads();
    for (int st = 128; st > 0; st >>= 1) {
        if (tid < st) red[tid] += red[tid + st];
        __syncthreads();
    }
    int blockOff = red[0];
    __syncthreads();

    __shared__ int ssum[256];
    ssum[tid] = lsum;
    __syncthreads();
    for (int off = 1; off < 256; off <<= 1) {
        int t = (tid >= off) ? ssum[tid - off] : 0;
        __syncthreads();
        ssum[tid] += t;
        __syncthreads();
    }
    int r = blockOff + (tid == 0 ? 0 : ssum[tid - 1]);

    #pragma unroll
    for (int q = 0; q < 4; q++) {
        int v = i0 + q;
        if (v < N) {
            int c = (q == 0) ? v0 : (q == 1) ? v1 : (q == 2) ? v2 : v3;
            float dv = rsqrtf((float)c);
            rd2[v] = make_int2(r, __float_as_int(dv));
            edata[r] = make_int2(v, __float_as_int(dv * dv));  // self-loop at slot 0
            r += c;
        }
    }
    if (b == gridDim.x - 1 && tid == 255) rd2[N] = make_int2(blockOff + ssum[255], 0);
}

// fill: block (c,r) re-ranks chunk c / range r via LDS atomics and scatters
// edata[row_start[d] + 1 + chunkpfx[c][d] + lrank]. No global atomics.
__global__ __launch_bounds__(256) void GCN_fill_k(const int* __restrict__ edge,
                                                  const int* __restrict__ chunkhist,
                                                  const int2* __restrict__ rd2,
                                                  int2* __restrict__ edata,
                                                  int N, int E, int nRange,
                                                  int qpr, int ech) {
    __shared__ int lhist[QPR_MAX];
    int tid = threadIdx.x;
    int c = blockIdx.x / nRange, r = blockIdx.x % nRange;
    for (int j = tid; j < qpr; j += 256) lhist[j] = 0;
    __syncthreads();
    int base = c * ech;
    int lim = base + ech; if (lim > E) lim = E;
    int r0 = r * qpr;
    for (int i = base + tid; i < lim; i += 256) {
        int d = edge[E + i];
        int dd = d - r0;
        if ((unsigned)dd < (unsigned)qpr) {
            int lrank = atomicAdd(&lhist[dd], 1);
            int s = edge[i];
            int2 rdd = rd2[d];
            float ds = __int_as_float(rd2[s].y);
            int slot = rdd.x + 1 + chunkhist[(size_t)c * N + d] + lrank;
            edata[slot] = make_int2(s, __float_as_int(ds * __int_as_float(rdd.y)));
        }
    }
}

// MEGA-B: agg1 (16 lanes/node, x4 unroll) -> h rows in LDS -> gemm2 fused.
// h2 written as bf16 (ushort), 32B/row.
__global__ __launch_bounds__(256) void GCN_agg1gemm2_k(
        const ushort* __restrict__ h1, const int2* __restrict__ rd2,
        const int2* __restrict__ ed, const float* __restrict__ b1,
        const float* __restrict__ W2, ushort* __restrict__ h2b, int N) {
    __shared__ float w2s[FH][FO];        // 8 KiB
    __shared__ float hs[16][FH + 4];     // 8.25 KiB
    int tid = threadIdx.x;
    #pragma unroll
    for (int j = 0; j < (FH * FO) / 256; j++) {
        int i = tid + j * 256;
        w2s[i >> 4][i & 15] = W2[i];
    }

    int node0 = blockIdx.x * 16;
    int local = tid >> 4;
    int j = tid & 15;             // 16B unit: cols 8j..8j+7
    int node = node0 + local;

    if (node < N) {
        int beg = rd2[node].x, end = rd2[node + 1].x;
        const uint4* hp = (const uint4*)h1;

        float a[8];
        #pragma unroll
        for (int t = 0; t < 8; t++) a[t] = 0.f;

        int i = beg;
        for (; i + 4 <= end; i += 4) {
            int2 e0 = ed[i + 0], e1 = ed[i + 1], e2 = ed[i + 2], e3 = ed[i + 3];
            float w0 = __int_as_float(e0.y), w1 = __int_as_float(e1.y);
            float w2 = __int_as_float(e2.y), w3 = __int_as_float(e3.y);
            uint4 g0 = hp[(size_t)e0.x * 16 + j];
            uint4 g1 = hp[(size_t)e1.x * 16 + j];
            uint4 g2 = hp[(size_t)e2.x * 16 + j];
            uint4 g3 = hp[(size_t)e3.x * 16 + j];
            #pragma unroll
            for (int q = 0; q < 4; q++) {
                uint u0 = (&g0.x)[q], u1 = (&g1.x)[q], u2 = (&g2.x)[q], u3 = (&g3.x)[q];
                a[q*2+0] += __uint_as_float(u0 << 16) * w0;
                a[q*2+1] += __uint_as_float(u0 & 0xFFFF0000u) * w0;
                a[q*2+0] += __uint_as_float(u1 << 16) * w1;
                a[q*2+1] += __uint_as_float(u1 & 0xFFFF0000u) * w1;
                a[q*2+0] += __uint_as_float(u2 << 16) * w2;
                a[q*2+1] += __uint_as_float(u2 & 0xFFFF0000u) * w2;
                a[q*2+0] += __uint_as_float(u3 << 16) * w3;
                a[q*2+1] += __uint_as_float(u3 & 0xFFFF0000u) * w3;
            }
        }
        for (; i < end; i++) {
            int2 e = ed[i];
            float w = __int_as_float(e.y);
            uint4 g = hp[(size_t)e.x * 16 + j];
            #pragma unroll
            for (int q = 0; q < 4; q++) {
                uint u = (&g.x)[q];
                a[q*2+0] += __uint_as_float(u << 16) * w;
                a[q*2+1] += __uint_as_float(u & 0xFFFF0000u) * w;
            }
        }

        const float4* bp = (const float4*)b1;
        float4 bb0 = bp[j * 2 + 0];
        float4 bb1 = bp[j * 2 + 1];
        float4 o0, o1;
        o0.x = fmaxf(a[0] + bb0.x, 0.f);
        o0.y = fmaxf(a[1] + bb0.y, 0.f);
        o0.z = fmaxf(a[2] + bb0.z, 0.f);
        o0.w = fmaxf(a[3] + bb0.w, 0.f);
        o1.x = fmaxf(a[4] + bb1.x, 0.f);
        o1.y = fmaxf(a[5] + bb1.y, 0.f);
        o1.z = fmaxf(a[6] + bb1.z, 0.f);
        o1.w = fmaxf(a[7] + bb1.w, 0.f);
        *(float4*)&hs[local][j * 8 + 0] = o0;
        *(float4*)&hs[local][j * 8 + 4] = o1;
    }
    __syncthreads();

    float acc = 0.f;
    #pragma unroll 8
    for (int k = 0; k < FH; k++) acc += hs[local][k] * w2s[k][j];
    if (node < N) h2b[(size_t)node * FO + j] = f2bf(acc);
}

// AGG2 (bf16 h2) + bias + log_softmax. 8 lanes/node, 2 cols/lane, x4 unroll.
__global__ __launch_bounds__(256) void GCN_agg2_k(const ushort* __restrict__ h2b,
                                                  const int2* __restrict__ rd2,
                                                  const int2* __restrict__ ed,
                                                  const float* __restrict__ b2,
                                                  float* __restrict__ out, int N) {
    int tid = threadIdx.x;
    int node = blockIdx.x * 32 + (tid >> 3);
    if (node >= N) return;
    int f2 = tid & 7;                        // cols 2*f2, 2*f2+1
    int beg = rd2[node].x, end = rd2[node + 1].x;
    const uint* hp = (const uint*)h2b;       // row = 8 uints (16 bf16)
    float a0 = 0.f, a1 = 0.f;
    int i = beg;
    for (; i + 4 <= end; i += 4) {
        int2 e0 = ed[i + 0], e1 = ed[i + 1], e2 = ed[i + 2], e3 = ed[i + 3];
        uint u0 = hp[(size_t)e0.x * 8 + f2];
        uint u1 = hp[(size_t)e1.x * 8 + f2];
        uint u2 = hp[(size_t)e2.x * 8 + f2];
        uint u3 = hp[(size_t)e3.x * 8 + f2];
        float w0 = __int_as_float(e0.y), w1 = __int_as_float(e1.y);
        float w2 = __int_as_float(e2.y), w3 = __int_as_float(e3.y);
        a0 += __uint_as_float(u0 << 16) * w0 + __uint_as_float(u1 << 16) * w1
            + __uint_as_float(u2 << 16) * w2 + __uint_as_float(u3 << 16) * w3;
        a1 += __uint_as_float(u0 & 0xFFFF0000u) * w0 + __uint_as_float(u1 & 0xFFFF0000u) * w1
            + __uint_as_float(u2 & 0xFFFF0000u) * w2 + __uint_as_float(u3 & 0xFFFF0000u) * w3;
    }
    for (; i < end; i++) {
        int2 e = ed[i];
        uint u = hp[(size_t)e.x * 8 + f2];
        float w = __int_as_float(e.y);
        a0 += __uint_as_float(u << 16) * w;
        a1 += __uint_as_float(u & 0xFFFF0000u) * w;
    }
    float2 bb = ((const float2*)b2)[f2];
    float v0 = a0 + bb.x;
    float v1 = a1 + bb.y;
    float mx = fmaxf(v0, v1);
    #pragma unroll
    for (int m = 4; m >= 1; m >>= 1) mx = fmaxf(mx, __shfl_xor(mx, m, 8));
    float s = expf(v0 - mx) + expf(v1 - mx);
    #pragma unroll
    for (int m = 4; m >= 1; m >>= 1) s += __shfl_xor(s, m, 8);
    float ls = logf(s);
    float2 o = make_float2(v0 - mx - ls, v1 - mx - ls);
    ((float2*)out)[(size_t)node * 8 + f2] = o;
}

extern "C" void kernel_launch(void* const* d_in, const int* in_sizes, int n_in,
                              void* d_out, int out_size, void* d_ws, size_t ws_size,
                              hipStream_t stream) {
    (void)n_in; (void)out_size; (void)ws_size;
    const float* x  = (const float*)d_in[0];
    const int*   edp = (const int*)d_in[1];
    const float* W1 = (const float*)d_in[2];
    const float* b1 = (const float*)d_in[3];
    const float* W2 = (const float*)d_in[4];
    const float* b2 = (const float*)d_in[5];
    float* out = (float*)d_out;

    int N = in_sizes[0] / FIN;   // 50000
    int E = in_sizes[1] / 2;     // 800000
    int M = E + N;
    int nScanBlocks = (N + SCAN_CHUNK - 1) / SCAN_CHUNK;
    int nRange = (N + QPR_MAX - 1) / QPR_MAX;        // 8
    int qpr = (N + nRange - 1) / nRange;             // 6250 (<= QPR_MAX)
    int ech = (E + NCHUNK - 1) / NCHUNK;             // 25000

    char* p = (char*)d_ws;
    auto take = [&](size_t bytes) -> char* {
        char* r = p;
        p += (bytes + 255) & ~(size_t)255;
        return r;
    };
    int*    count     = (int*)take((size_t)N * 4);
    int*    chunkhist = (int*)take((size_t)NCHUNK * N * 4);
    int2*   rd2       = (int2*)take((size_t)(N + 1) * 8);
    int*    bsum      = (int*)take((size_t)nScanBlocks * 4);
    int2*   edata     = (int2*)take((size_t)M * 8);
    ushort* whT       = (ushort*)take((size_t)FH * FIN * 2);
    ushort* wlT       = (ushort*)take((size_t)FH * FIN * 2);
    ushort* h1        = (ushort*)take((size_t)N * FH * 2);
    ushort* h2b       = (ushort*)take((size_t)N * FO * 2);

    int nGemm  = (N + G1_BR - 1) / G1_BR;    // 782
    int nHrank = NCHUNK * nRange;            // 256

    GCN_wprep_k<<<(FIN * FH) / 256, 256, 0, stream>>>(W1, whT, wlT);
    GCN_gemmhrank_k<<<nGemm + nHrank, 256, 0, stream>>>(
        x, whT, wlT, h1, edp, chunkhist, N, E, nGemm, nRange, qpr, ech);
    GCN_chpfxbsum_k<<<nScanBlocks, 256, 0, stream>>>(chunkhist, count, bsum, N);
    GCN_scan2_k<<<nScanBlocks, 256, 0, stream>>>(count, bsum, rd2, edata, N);
    GCN_fill_k<<<nHrank, 256, 0, stream>>>(edp, chunkhist, rd2, edata, N, E, nRange, qpr, ech);
    GCN_agg1gemm2_k<<<(N + 15) / 16, 256, 0, stream>>>(h1, rd2, edata, b1, W2, h2b, N);
    GCN_agg2_k<<<(N + 31) / 32, 256, 0, stream>>>(h2b, rd2, edata, b2, out, N);
}

// Round 14
// 140.718 us; speedup vs baseline: 1.2682x; 1.2682x over previous
//
#include <hip/hip_runtime.h>
#include <hip/hip_bf16.h>
#include <math.h>

// ---------------------------------------------------------------------------
// GCN 2-layer forward. Pipeline (7 dispatches, ZERO global atomics):
//   1) wprep: W1^T -> bf16 hi/lo split
//   2) gemmhrank: GEMM1 (MFMA, 3-pass split bf16) || hrank (128 chunks x 8
//      dst-ranges, LDS histogram -> chunkhist[c][d])
//   3) chpfxbsum: chunkhist -> in-place per-chunk prefix; count[d]; bsum
//      (1 node/thread, 196 blocks)
//   4) scan2 -> rd2 = {row_start, dinv}; seeds self-loop edata (1 node/thread)
//   5) fill: LDS re-rank (1024 blocks, XCD-pinned ranges) -> edata scatter
//   6) MEGA-B: agg1 (gather+bias+relu) -> h in LDS -> gemm2 -> h2 (bf16)
//   7) AGG2 (bf16 h2, 8 lanes/node) + bias + log_softmax fused
// ---------------------------------------------------------------------------

#define FIN 256
#define FH  128
#define FO  16
#define NCHUNK 128         // edge chunks (grid = NCHUNK*NRANGE = 1024 blocks)
#define QPR_MAX 6272       // max nodes per dst-range (25088 B LDS histogram)

typedef unsigned int uint;
typedef unsigned short ushort;
typedef __attribute__((ext_vector_type(8))) short bf16x8;
typedef __attribute__((ext_vector_type(4))) float f32x4;

static __device__ __forceinline__ ushort f2bf(float f) {
    __hip_bfloat16 b = __float2bfloat16(f);
    return *reinterpret_cast<ushort*>(&b);
}
static __device__ __forceinline__ float bf2f(ushort u) {
    return __uint_as_float(((uint)u) << 16);
}

// W-prep: W1[256][128] fp32 -> whT/wlT [128 cols][256 k] bf16 hi/lo split.
__global__ __launch_bounds__(256) void GCN_wprep_k(const float* __restrict__ W1,
                                                   ushort* __restrict__ whT,
                                                   ushort* __restrict__ wlT) {
    int i = blockIdx.x * 256 + threadIdx.x;   // 32768
    int k = i >> 7, c = i & 127;
    float w = W1[i];
    ushort hh = f2bf(w);
    ushort hl = f2bf(w - bf2f(hh));
    whT[c * 256 + k] = hh;
    wlT[c * 256 + k] = hl;
}

// GEMM1 tile params
#define G1_BR 64
#define G1_KC 32

// blocks [0,nGemm): GEMM1; blocks [nGemm, nGemm + NCHUNK*nRange): hrank.
__global__ __launch_bounds__(256, 4) void GCN_gemmhrank_k(
        const float* __restrict__ x, const ushort* __restrict__ whT,
        const ushort* __restrict__ wlT, ushort* __restrict__ h1,
        const int* __restrict__ edge, int* __restrict__ chunkhist,
        int N, int E, int nGemm, int nRange, int qpr, int ech) {
    __shared__ __align__(16) char smem[QPR_MAX * 4];   // 25088 B
    int tid = threadIdx.x;

    if ((int)blockIdx.x >= nGemm) {
        // ---- hrank path: block (c,r) histograms chunk c, dst-range r ----
        int bid = blockIdx.x - nGemm;
        int c = bid / nRange, r = bid % nRange;
        int* lhist = (int*)smem;
        for (int j = tid; j < qpr; j += 256) lhist[j] = 0;
        __syncthreads();
        int base = c * ech;
        int lim = base + ech; if (lim > E) lim = E;
        int r0 = r * qpr;
        for (int i = base + tid; i < lim; i += 256) {
            int d = edge[E + i];
            int dd = d - r0;
            if ((unsigned)dd < (unsigned)qpr) atomicAdd(&lhist[dd], 1);
        }
        __syncthreads();
        for (int j = tid; j < qpr; j += 256) {
            int d = r0 + j;
            if (d < N) chunkhist[(size_t)c * N + d] = lhist[j];
        }
        return;
    }

    // ---- gemm1 path ----
    ushort* xh_s = (ushort*)smem;              // 4 KiB
    ushort* xl_s = (ushort*)(smem + 4096);     // 4 KiB
    ushort* wh_s = (ushort*)(smem + 8192);     // 8 KiB
    ushort* wl_s = (ushort*)(smem + 16384);    // 8 KiB
    int row0 = blockIdx.x * G1_BR;
    int ln = tid & 63;
    int w  = tid >> 6;          // wave 0..3 -> col slab w*32
    int ln15 = ln & 15;
    int q16  = ln >> 4;         // k-slot 0..3

    f32x4 acc[4][2];
    #pragma unroll
    for (int mr = 0; mr < 4; mr++)
        #pragma unroll
        for (int nc = 0; nc < 2; nc++) acc[mr][nc] = (f32x4){0.f, 0.f, 0.f, 0.f};

    for (int kc = 0; kc < FIN; kc += G1_KC) {
        #pragma unroll
        for (int j = 0; j < 2; j++) {
            int u = tid + j * 256;
            int r = u >> 3, kq = u & 7;       // 8 float4 per row
            int gr = row0 + r;
            float4 v = make_float4(0.f, 0.f, 0.f, 0.f);
            if (gr < N) v = *(const float4*)&x[(size_t)gr * FIN + kc + kq * 4];
            ushort h0 = f2bf(v.x), h1v = f2bf(v.y), h2 = f2bf(v.z), h3 = f2bf(v.w);
            ushort l0 = f2bf(v.x - bf2f(h0));
            ushort l1 = f2bf(v.y - bf2f(h1v));
            ushort l2 = f2bf(v.z - bf2f(h2));
            ushort l3 = f2bf(v.w - bf2f(h3));
            uint2 hw, lw;
            hw.x = (uint)h0 | ((uint)h1v << 16);
            hw.y = (uint)h2 | ((uint)h3 << 16);
            lw.x = (uint)l0 | ((uint)l1 << 16);
            lw.y = (uint)l2 | ((uint)l3 << 16);
            int byte = (r * 64 + kq * 8) ^ (((r >> 1) & 3) << 4);
            *(uint2*)((char*)xh_s + byte) = hw;
            *(uint2*)((char*)xl_s + byte) = lw;
        }
        #pragma unroll
        for (int j = 0; j < 2; j++) {
            int u = tid + j * 256;
            int c = u >> 2, ku = u & 3;       // 4 x 16B per col
            uint4 vh = *(const uint4*)&whT[(size_t)c * 256 + kc + ku * 8];
            uint4 vl = *(const uint4*)&wlT[(size_t)c * 256 + kc + ku * 8];
            int byte = (c * 64 + ku * 16) ^ (((c >> 1) & 3) << 4);
            *(uint4*)((char*)wh_s + byte) = vh;
            *(uint4*)((char*)wl_s + byte) = vl;
        }
        __syncthreads();

        bf16x8 ah[4], al[4], bh[2], bl[2];
        #pragma unroll
        for (int mr = 0; mr < 4; mr++) {
            int r = mr * 16 + ln15;
            int byte = r * 64 + ((q16 * 16) ^ (((r >> 1) & 3) << 4));
            ah[mr] = *(const bf16x8*)((const char*)xh_s + byte);
            al[mr] = *(const bf16x8*)((const char*)xl_s + byte);
        }
        #pragma unroll
        for (int nc = 0; nc < 2; nc++) {
            int c = w * 32 + nc * 16 + ln15;
            int byte = c * 64 + ((q16 * 16) ^ (((c >> 1) & 3) << 4));
            bh[nc] = *(const bf16x8*)((const char*)wh_s + byte);
            bl[nc] = *(const bf16x8*)((const char*)wl_s + byte);
        }
        #pragma unroll
        for (int mr = 0; mr < 4; mr++)
            #pragma unroll
            for (int nc = 0; nc < 2; nc++) {
                acc[mr][nc] = __builtin_amdgcn_mfma_f32_16x16x32_bf16(
                    ah[mr], bh[nc], acc[mr][nc], 0, 0, 0);
                acc[mr][nc] = __builtin_amdgcn_mfma_f32_16x16x32_bf16(
                    al[mr], bh[nc], acc[mr][nc], 0, 0, 0);
                acc[mr][nc] = __builtin_amdgcn_mfma_f32_16x16x32_bf16(
                    ah[mr], bl[nc], acc[mr][nc], 0, 0, 0);
            }
        __syncthreads();
    }

    // epilogue: D layout col=lane&15, row=(lane>>4)*4+reg  [m89-verified]
    #pragma unroll
    for (int mr = 0; mr < 4; mr++) {
        #pragma unroll
        for (int nc = 0; nc < 2; nc++) {
            int cw = w * 32 + nc * 16 + ln15;
            #pragma unroll
            for (int j = 0; j < 4; j++) {
                int gr = row0 + mr * 16 + q16 * 4 + j;
                if (gr < N) h1[(size_t)gr * FH + cw] = f2bf(acc[mr][nc][j]);
            }
        }
    }
}

// chpfxbsum: 1 node/thread. chunkhist[c][d] -> exclusive prefix over c;
// count[d] = total; bsum[blk] = sum(count+1) over the block's 256 nodes.
__global__ __launch_bounds__(256) void GCN_chpfxbsum_k(int* __restrict__ chunkhist,
                                                       int* __restrict__ count,
                                                       int* __restrict__ bsum,
                                                       int N) {
    int tid = threadIdx.x;
    int d = blockIdx.x * 256 + tid;
    int local = 0;
    if (d < N) {
        int run = 0;
        #pragma unroll 8
        for (int c = 0; c < NCHUNK; c++) {
            int* p = &chunkhist[(size_t)c * N + d];
            int v = *p; *p = run; run += v;
        }
        count[d] = run;
        local = run + 1;
    }
    __shared__ int red[256];
    red[tid] = local;
    __syncthreads();
    for (int st = 128; st > 0; st >>= 1) {
        if (tid < st) red[tid] += red[tid + st];
        __syncthreads();
    }
    if (tid == 0) bsum[blockIdx.x] = red[0];
}

// scan2: 1 node/thread. rd2[v] = {row_start[v], bits(dinv[v])}; rd2[N].x =
// total; seeds self-loop entry edata[row_start[v]] = {v, dinv^2}.
__global__ __launch_bounds__(256) void GCN_scan2_k(const int* __restrict__ count,
                                                   const int* __restrict__ bsum,
                                                   int2* __restrict__ rd2,
                                                   int2* __restrict__ edata, int N) {
    int tid = threadIdx.x;
    int b = blockIdx.x;
    int d = b * 256 + tid;
    int cnt1 = (d < N) ? count[d] + 1 : 0;

    __shared__ int red[256];
    int offp = 0;
    for (int t = tid; t < b; t += 256) offp += bsum[t];
    red[tid] = offp;
    __syncthreads();
    for (int st = 128; st > 0; st >>= 1) {
        if (tid < st) red[tid] += red[tid + st];
        __syncthreads();
    }
    int blockOff = red[0];
    __syncthreads();

    __shared__ int ssum[256];
    ssum[tid] = cnt1;
    __syncthreads();
    for (int off = 1; off < 256; off <<= 1) {
        int t = (tid >= off) ? ssum[tid - off] : 0;
        __syncthreads();
        ssum[tid] += t;
        __syncthreads();
    }
    int r = blockOff + ssum[tid] - cnt1;   // exclusive

    if (d < N) {
        float dv = rsqrtf((float)cnt1);
        rd2[d] = make_int2(r, __float_as_int(dv));
        edata[r] = make_int2(d, __float_as_int(dv * dv));  // self-loop at slot 0
    }
    if (b == gridDim.x - 1 && tid == 255) rd2[N] = make_int2(blockOff + ssum[255], 0);
}

// fill: block (c,r) re-ranks chunk c / range r via LDS atomics and scatters
// edata[row_start[d] + 1 + chunkpfx[c][d] + lrank]. No global atomics.
// r = blockIdx % 8 -> consecutive blocks different ranges -> each range's
// edata/rd2/chunkhist window XCD-pinned under round-robin placement.
__global__ __launch_bounds__(256) void GCN_fill_k(const int* __restrict__ edge,
                                                  const int* __restrict__ chunkhist,
                                                  const int2* __restrict__ rd2,
                                                  int2* __restrict__ edata,
                                                  int N, int E, int nRange,
                                                  int qpr, int ech) {
    __shared__ int lhist[QPR_MAX];
    int tid = threadIdx.x;
    int r = blockIdx.x % nRange, c = blockIdx.x / nRange;
    for (int j = tid; j < qpr; j += 256) lhist[j] = 0;
    __syncthreads();
    int base = c * ech;
    int lim = base + ech; if (lim > E) lim = E;
    int r0 = r * qpr;
    for (int i = base + tid; i < lim; i += 256) {
        int d = edge[E + i];
        int dd = d - r0;
        if ((unsigned)dd < (unsigned)qpr) {
            int lrank = atomicAdd(&lhist[dd], 1);
            int s = edge[i];
            int2 rdd = rd2[d];
            float ds = __int_as_float(rd2[s].y);
            int slot = rdd.x + 1 + chunkhist[(size_t)c * N + d] + lrank;
            edata[slot] = make_int2(s, __float_as_int(ds * __int_as_float(rdd.y)));
        }
    }
}

// MEGA-B: agg1 (16 lanes/node, x4 unroll) -> h rows in LDS -> gemm2 fused.
// h2 written as bf16 (ushort), 32B/row.
__global__ __launch_bounds__(256) void GCN_agg1gemm2_k(
        const ushort* __restrict__ h1, const int2* __restrict__ rd2,
        const int2* __restrict__ ed, const float* __restrict__ b1,
        const float* __restrict__ W2, ushort* __restrict__ h2b, int N) {
    __shared__ float w2s[FH][FO];        // 8 KiB
    __shared__ float hs[16][FH + 4];     // 8.25 KiB
    int tid = threadIdx.x;
    #pragma unroll
    for (int j = 0; j < (FH * FO) / 256; j++) {
        int i = tid + j * 256;
        w2s[i >> 4][i & 15] = W2[i];
    }

    int node0 = blockIdx.x * 16;
    int local = tid >> 4;
    int j = tid & 15;             // 16B unit: cols 8j..8j+7
    int node = node0 + local;

    if (node < N) {
        int beg = rd2[node].x, end = rd2[node + 1].x;
        const uint4* hp = (const uint4*)h1;

        float a[8];
        #pragma unroll
        for (int t = 0; t < 8; t++) a[t] = 0.f;

        int i = beg;
        for (; i + 4 <= end; i += 4) {
            int2 e0 = ed[i + 0], e1 = ed[i + 1], e2 = ed[i + 2], e3 = ed[i + 3];
            float w0 = __int_as_float(e0.y), w1 = __int_as_float(e1.y);
            float w2 = __int_as_float(e2.y), w3 = __int_as_float(e3.y);
            uint4 g0 = hp[(size_t)e0.x * 16 + j];
            uint4 g1 = hp[(size_t)e1.x * 16 + j];
            uint4 g2 = hp[(size_t)e2.x * 16 + j];
            uint4 g3 = hp[(size_t)e3.x * 16 + j];
            #pragma unroll
            for (int q = 0; q < 4; q++) {
                uint u0 = (&g0.x)[q], u1 = (&g1.x)[q], u2 = (&g2.x)[q], u3 = (&g3.x)[q];
                a[q*2+0] += __uint_as_float(u0 << 16) * w0;
                a[q*2+1] += __uint_as_float(u0 & 0xFFFF0000u) * w0;
                a[q*2+0] += __uint_as_float(u1 << 16) * w1;
                a[q*2+1] += __uint_as_float(u1 & 0xFFFF0000u) * w1;
                a[q*2+0] += __uint_as_float(u2 << 16) * w2;
                a[q*2+1] += __uint_as_float(u2 & 0xFFFF0000u) * w2;
                a[q*2+0] += __uint_as_float(u3 << 16) * w3;
                a[q*2+1] += __uint_as_float(u3 & 0xFFFF0000u) * w3;
            }
        }
        for (; i < end; i++) {
            int2 e = ed[i];
            float w = __int_as_float(e.y);
            uint4 g = hp[(size_t)e.x * 16 + j];
            #pragma unroll
            for (int q = 0; q < 4; q++) {
                uint u = (&g.x)[q];
                a[q*2+0] += __uint_as_float(u << 16) * w;
                a[q*2+1] += __uint_as_float(u & 0xFFFF0000u) * w;
            }
        }

        const float4* bp = (const float4*)b1;
        float4 bb0 = bp[j * 2 + 0];
        float4 bb1 = bp[j * 2 + 1];
        float4 o0, o1;
        o0.x = fmaxf(a[0] + bb0.x, 0.f);
        o0.y = fmaxf(a[1] + bb0.y, 0.f);
        o0.z = fmaxf(a[2] + bb0.z, 0.f);
        o0.w = fmaxf(a[3] + bb0.w, 0.f);
        o1.x = fmaxf(a[4] + bb1.x, 0.f);
        o1.y = fmaxf(a[5] + bb1.y, 0.f);
        o1.z = fmaxf(a[6] + bb1.z, 0.f);
        o1.w = fmaxf(a[7] + bb1.w, 0.f);
        *(float4*)&hs[local][j * 8 + 0] = o0;
        *(float4*)&hs[local][j * 8 + 4] = o1;
    }
    __syncthreads();

    float acc = 0.f;
    #pragma unroll 8
    for (int k = 0; k < FH; k++) acc += hs[local][k] * w2s[k][j];
    if (node < N) h2b[(size_t)node * FO + j] = f2bf(acc);
}

// AGG2 (bf16 h2) + bias + log_softmax. 8 lanes/node, 2 cols/lane, x4 unroll.
__global__ __launch_bounds__(256) void GCN_agg2_k(const ushort* __restrict__ h2b,
                                                  const int2* __restrict__ rd2,
                                                  const int2* __restrict__ ed,
                                                  const float* __restrict__ b2,
                                                  float* __restrict__ out, int N) {
    int tid = threadIdx.x;
    int node = blockIdx.x * 32 + (tid >> 3);
    if (node >= N) return;
    int f2 = tid & 7;                        // cols 2*f2, 2*f2+1
    int beg = rd2[node].x, end = rd2[node + 1].x;
    const uint* hp = (const uint*)h2b;       // row = 8 uints (16 bf16)
    float a0 = 0.f, a1 = 0.f;
    int i = beg;
    for (; i + 4 <= end; i += 4) {
        int2 e0 = ed[i + 0], e1 = ed[i + 1], e2 = ed[i + 2], e3 = ed[i + 3];
        uint u0 = hp[(size_t)e0.x * 8 + f2];
        uint u1 = hp[(size_t)e1.x * 8 + f2];
        uint u2 = hp[(size_t)e2.x * 8 + f2];
        uint u3 = hp[(size_t)e3.x * 8 + f2];
        float w0 = __int_as_float(e0.y), w1 = __int_as_float(e1.y);
        float w2 = __int_as_float(e2.y), w3 = __int_as_float(e3.y);
        a0 += __uint_as_float(u0 << 16) * w0 + __uint_as_float(u1 << 16) * w1
            + __uint_as_float(u2 << 16) * w2 + __uint_as_float(u3 << 16) * w3;
        a1 += __uint_as_float(u0 & 0xFFFF0000u) * w0 + __uint_as_float(u1 & 0xFFFF0000u) * w1
            + __uint_as_float(u2 & 0xFFFF0000u) * w2 + __uint_as_float(u3 & 0xFFFF0000u) * w3;
    }
    for (; i < end; i++) {
        int2 e = ed[i];
        uint u = hp[(size_t)e.x * 8 + f2];
        float w = __int_as_float(e.y);
        a0 += __uint_as_float(u << 16) * w;
        a1 += __uint_as_float(u & 0xFFFF0000u) * w;
    }
    float2 bb = ((const float2*)b2)[f2];
    float v0 = a0 + bb.x;
    float v1 = a1 + bb.y;
    float mx = fmaxf(v0, v1);
    #pragma unroll
    for (int m = 4; m >= 1; m >>= 1) mx = fmaxf(mx, __shfl_xor(mx, m, 8));
    float s = expf(v0 - mx) + expf(v1 - mx);
    #pragma unroll
    for (int m = 4; m >= 1; m >>= 1) s += __shfl_xor(s, m, 8);
    float ls = logf(s);
    float2 o = make_float2(v0 - mx - ls, v1 - mx - ls);
    ((float2*)out)[(size_t)node * 8 + f2] = o;
}

extern "C" void kernel_launch(void* const* d_in, const int* in_sizes, int n_in,
                              void* d_out, int out_size, void* d_ws, size_t ws_size,
                              hipStream_t stream) {
    (void)n_in; (void)out_size; (void)ws_size;
    const float* x  = (const float*)d_in[0];
    const int*   edp = (const int*)d_in[1];
    const float* W1 = (const float*)d_in[2];
    const float* b1 = (const float*)d_in[3];
    const float* W2 = (const float*)d_in[4];
    const float* b2 = (const float*)d_in[5];
    float* out = (float*)d_out;

    int N = in_sizes[0] / FIN;   // 50000
    int E = in_sizes[1] / 2;     // 800000
    int M = E + N;
    int nScanBlocks = (N + 255) / 256;               // 196 (1 node/thread)
    int nRange = (N + QPR_MAX - 1) / QPR_MAX;        // 8
    int qpr = (N + nRange - 1) / nRange;             // 6250 (<= QPR_MAX)
    int ech = (E + NCHUNK - 1) / NCHUNK;             // 6250

    char* p = (char*)d_ws;
    auto take = [&](size_t bytes) -> char* {
        char* r = p;
        p += (bytes + 255) & ~(size_t)255;
        return r;
    };
    int*    count     = (int*)take((size_t)N * 4);
    int*    chunkhist = (int*)take((size_t)NCHUNK * N * 4);   // 25.6 MB
    int2*   rd2       = (int2*)take((size_t)(N + 1) * 8);
    int*    bsum      = (int*)take((size_t)nScanBlocks * 4);
    int2*   edata     = (int2*)take((size_t)M * 8);
    ushort* whT       = (ushort*)take((size_t)FH * FIN * 2);
    ushort* wlT       = (ushort*)take((size_t)FH * FIN * 2);
    ushort* h1        = (ushort*)take((size_t)N * FH * 2);
    ushort* h2b       = (ushort*)take((size_t)N * FO * 2);

    int nGemm  = (N + G1_BR - 1) / G1_BR;    // 782
    int nHrank = NCHUNK * nRange;            // 1024

    GCN_wprep_k<<<(FIN * FH) / 256, 256, 0, stream>>>(W1, whT, wlT);
    GCN_gemmhrank_k<<<nGemm + nHrank, 256, 0, stream>>>(
        x, whT, wlT, h1, edp, chunkhist, N, E, nGemm, nRange, qpr, ech);
    GCN_chpfxbsum_k<<<nScanBlocks, 256, 0, stream>>>(chunkhist, count, bsum, N);
    GCN_scan2_k<<<nScanBlocks, 256, 0, stream>>>(count, bsum, rd2, edata, N);
    GCN_fill_k<<<nHrank, 256, 0, stream>>>(edp, chunkhist, rd2, edata, N, E, nRange, qpr, ech);
    GCN_agg1gemm2_k<<<(N + 15) / 16, 256, 0, stream>>>(h1, rd2, edata, b1, W2, h2b, N);
    GCN_agg2_k<<<(N + 31) / 32, 256, 0, stream>>>(h2b, rd2, edata, b2, out, N);
}

// Round 15
// 137.822 us; speedup vs baseline: 1.2948x; 1.0210x over previous
//
#include <hip/hip_runtime.h>
#include <hip/hip_bf16.h>
#include <math.h>

// ---------------------------------------------------------------------------
// GCN 2-layer forward. Pipeline (6 dispatches, ZERO global atomics):
//   1) wprep: W1^T -> bf16 hi/lo split
//   2) hrankgemm: hrank FIRST (128 chunks x 8 ranges: LDS histogram ->
//      chunkhist[c][d], lrank[i] = LDS-atomic rank) || GEMM1 backfills
//   3) chpfxbsum: chunkhist -> in-place per-chunk prefix; count[d]; bsum
//   4) scan2 -> rd2 = {row_start, dinv}; seeds self-loop edata
//   5) fill: DIRECT scatter edata[rs[d]+1+chunkpfx[c][d]+lrank[i]]
//   6) MEGA-B: agg1 -> h in LDS -> gemm2 -> h2 (bf16)
//   7) AGG2 (bf16 h2, 8 lanes/node) + bias + log_softmax fused
// ---------------------------------------------------------------------------

#define FIN 256
#define FH  128
#define FO  16
#define NCHUNK 128         // edge chunks
#define QPR_MAX 6272       // max nodes per dst-range (25088 B LDS histogram)

typedef unsigned int uint;
typedef unsigned short ushort;
typedef __attribute__((ext_vector_type(8))) short bf16x8;
typedef __attribute__((ext_vector_type(4))) float f32x4;

static __device__ __forceinline__ ushort f2bf(float f) {
    __hip_bfloat16 b = __float2bfloat16(f);
    return *reinterpret_cast<ushort*>(&b);
}
static __device__ __forceinline__ float bf2f(ushort u) {
    return __uint_as_float(((uint)u) << 16);
}

// W-prep: W1[256][128] fp32 -> whT/wlT [128 cols][256 k] bf16 hi/lo split.
__global__ __launch_bounds__(256) void GCN_wprep_k(const float* __restrict__ W1,
                                                   ushort* __restrict__ whT,
                                                   ushort* __restrict__ wlT) {
    int i = blockIdx.x * 256 + threadIdx.x;   // 32768
    int k = i >> 7, c = i & 127;
    float w = W1[i];
    ushort hh = f2bf(w);
    ushort hl = f2bf(w - bf2f(hh));
    whT[c * 256 + k] = hh;
    wlT[c * 256 + k] = hl;
}

// GEMM1 tile params
#define G1_BR 64
#define G1_KC 32

// blocks [0, nHrank): hrank (flood CUs first); [nHrank, +nGemm): GEMM1.
// hrank block (c,r): LDS-histogram chunk c's edges with dst in range r;
// lrank[i] = local rank (LDS atomic return); flush hist -> chunkhist[c][d].
// GEMM1: h1(bf16)[N][128] = x @ W1, 3-pass split-bf16 MFMA, KC=32,
// LDS rows 64B, swizzle byte^=((r>>1)&3)<<4.
__global__ __launch_bounds__(256, 4) void GCN_hrankgemm_k(
        const float* __restrict__ x, const ushort* __restrict__ whT,
        const ushort* __restrict__ wlT, ushort* __restrict__ h1,
        const int* __restrict__ edge, int* __restrict__ chunkhist,
        int* __restrict__ lrank,
        int N, int E, int nHrank, int nRange, int qpr, int ech) {
    __shared__ __align__(16) char smem[QPR_MAX * 4];   // 25088 B
    int tid = threadIdx.x;

    if ((int)blockIdx.x < nHrank) {
        // ---- hrank path ----
        int bid = blockIdx.x;
        int c = bid / nRange, r = bid % nRange;
        int* lhist = (int*)smem;
        for (int j = tid; j < qpr; j += 256) lhist[j] = 0;
        __syncthreads();
        int base = c * ech;
        int lim = base + ech; if (lim > E) lim = E;
        int r0 = r * qpr;
        for (int i = base + tid; i < lim; i += 256) {
            int d = edge[E + i];
            int dd = d - r0;
            if ((unsigned)dd < (unsigned)qpr)
                lrank[i] = atomicAdd(&lhist[dd], 1);
        }
        __syncthreads();
        for (int j = tid; j < qpr; j += 256) {
            int d = r0 + j;
            if (d < N) chunkhist[(size_t)c * N + d] = lhist[j];
        }
        return;
    }

    // ---- gemm1 path ----
    ushort* xh_s = (ushort*)smem;              // 4 KiB
    ushort* xl_s = (ushort*)(smem + 4096);     // 4 KiB
    ushort* wh_s = (ushort*)(smem + 8192);     // 8 KiB
    ushort* wl_s = (ushort*)(smem + 16384);    // 8 KiB
    int row0 = (blockIdx.x - nHrank) * G1_BR;
    int ln = tid & 63;
    int w  = tid >> 6;          // wave 0..3 -> col slab w*32
    int ln15 = ln & 15;
    int q16  = ln >> 4;         // k-slot 0..3

    f32x4 acc[4][2];
    #pragma unroll
    for (int mr = 0; mr < 4; mr++)
        #pragma unroll
        for (int nc = 0; nc < 2; nc++) acc[mr][nc] = (f32x4){0.f, 0.f, 0.f, 0.f};

    for (int kc = 0; kc < FIN; kc += G1_KC) {
        #pragma unroll
        for (int j = 0; j < 2; j++) {
            int u = tid + j * 256;
            int r = u >> 3, kq = u & 7;       // 8 float4 per row
            int gr = row0 + r;
            float4 v = make_float4(0.f, 0.f, 0.f, 0.f);
            if (gr < N) v = *(const float4*)&x[(size_t)gr * FIN + kc + kq * 4];
            ushort h0 = f2bf(v.x), h1v = f2bf(v.y), h2 = f2bf(v.z), h3 = f2bf(v.w);
            ushort l0 = f2bf(v.x - bf2f(h0));
            ushort l1 = f2bf(v.y - bf2f(h1v));
            ushort l2 = f2bf(v.z - bf2f(h2));
            ushort l3 = f2bf(v.w - bf2f(h3));
            uint2 hw, lw;
            hw.x = (uint)h0 | ((uint)h1v << 16);
            hw.y = (uint)h2 | ((uint)h3 << 16);
            lw.x = (uint)l0 | ((uint)l1 << 16);
            lw.y = (uint)l2 | ((uint)l3 << 16);
            int byte = (r * 64 + kq * 8) ^ (((r >> 1) & 3) << 4);
            *(uint2*)((char*)xh_s + byte) = hw;
            *(uint2*)((char*)xl_s + byte) = lw;
        }
        #pragma unroll
        for (int j = 0; j < 2; j++) {
            int u = tid + j * 256;
            int c = u >> 2, ku = u & 3;       // 4 x 16B per col
            uint4 vh = *(const uint4*)&whT[(size_t)c * 256 + kc + ku * 8];
            uint4 vl = *(const uint4*)&wlT[(size_t)c * 256 + kc + ku * 8];
            int byte = (c * 64 + ku * 16) ^ (((c >> 1) & 3) << 4);
            *(uint4*)((char*)wh_s + byte) = vh;
            *(uint4*)((char*)wl_s + byte) = vl;
        }
        __syncthreads();

        bf16x8 ah[4], al[4], bh[2], bl[2];
        #pragma unroll
        for (int mr = 0; mr < 4; mr++) {
            int r = mr * 16 + ln15;
            int byte = r * 64 + ((q16 * 16) ^ (((r >> 1) & 3) << 4));
            ah[mr] = *(const bf16x8*)((const char*)xh_s + byte);
            al[mr] = *(const bf16x8*)((const char*)xl_s + byte);
        }
        #pragma unroll
        for (int nc = 0; nc < 2; nc++) {
            int c = w * 32 + nc * 16 + ln15;
            int byte = c * 64 + ((q16 * 16) ^ (((c >> 1) & 3) << 4));
            bh[nc] = *(const bf16x8*)((const char*)wh_s + byte);
            bl[nc] = *(const bf16x8*)((const char*)wl_s + byte);
        }
        #pragma unroll
        for (int mr = 0; mr < 4; mr++)
            #pragma unroll
            for (int nc = 0; nc < 2; nc++) {
                acc[mr][nc] = __builtin_amdgcn_mfma_f32_16x16x32_bf16(
                    ah[mr], bh[nc], acc[mr][nc], 0, 0, 0);
                acc[mr][nc] = __builtin_amdgcn_mfma_f32_16x16x32_bf16(
                    al[mr], bh[nc], acc[mr][nc], 0, 0, 0);
                acc[mr][nc] = __builtin_amdgcn_mfma_f32_16x16x32_bf16(
                    ah[mr], bl[nc], acc[mr][nc], 0, 0, 0);
            }
        __syncthreads();
    }

    // epilogue: D layout col=lane&15, row=(lane>>4)*4+reg  [m89-verified]
    #pragma unroll
    for (int mr = 0; mr < 4; mr++) {
        #pragma unroll
        for (int nc = 0; nc < 2; nc++) {
            int cw = w * 32 + nc * 16 + ln15;
            #pragma unroll
            for (int j = 0; j < 4; j++) {
                int gr = row0 + mr * 16 + q16 * 4 + j;
                if (gr < N) h1[(size_t)gr * FH + cw] = f2bf(acc[mr][nc][j]);
            }
        }
    }
}

// chpfxbsum: 1 node/thread. chunkhist[c][d] -> exclusive prefix over c
// (coalesced across threads per c); count[d] = total; bsum per block.
__global__ __launch_bounds__(256) void GCN_chpfxbsum_k(int* __restrict__ chunkhist,
                                                       int* __restrict__ count,
                                                       int* __restrict__ bsum,
                                                       int N) {
    int tid = threadIdx.x;
    int d = blockIdx.x * 256 + tid;
    int local = 0;
    if (d < N) {
        int run = 0;
        #pragma unroll 8
        for (int c = 0; c < NCHUNK; c++) {
            int* p = &chunkhist[(size_t)c * N + d];
            int v = *p; *p = run; run += v;
        }
        count[d] = run;
        local = run + 1;
    }
    __shared__ int red[256];
    red[tid] = local;
    __syncthreads();
    for (int st = 128; st > 0; st >>= 1) {
        if (tid < st) red[tid] += red[tid + st];
        __syncthreads();
    }
    if (tid == 0) bsum[blockIdx.x] = red[0];
}

// scan2: 1 node/thread. rd2[v] = {row_start[v], bits(dinv[v])}; rd2[N].x =
// total; seeds self-loop entry edata[row_start[v]] = {v, dinv^2}.
__global__ __launch_bounds__(256) void GCN_scan2_k(const int* __restrict__ count,
                                                   const int* __restrict__ bsum,
                                                   int2* __restrict__ rd2,
                                                   int2* __restrict__ edata, int N) {
    int tid = threadIdx.x;
    int b = blockIdx.x;
    int d = b * 256 + tid;
    int cnt1 = (d < N) ? count[d] + 1 : 0;

    __shared__ int red[256];
    int offp = 0;
    for (int t = tid; t < b; t += 256) offp += bsum[t];
    red[tid] = offp;
    __syncthreads();
    for (int st = 128; st > 0; st >>= 1) {
        if (tid < st) red[tid] += red[tid + st];
        __syncthreads();
    }
    int blockOff = red[0];
    __syncthreads();

    __shared__ int ssum[256];
    ssum[tid] = cnt1;
    __syncthreads();
    for (int off = 1; off < 256; off <<= 1) {
        int t = (tid >= off) ? ssum[tid - off] : 0;
        __syncthreads();
        ssum[tid] += t;
        __syncthreads();
    }
    int r = blockOff + ssum[tid] - cnt1;   // exclusive

    if (d < N) {
        float dv = rsqrtf((float)cnt1);
        rd2[d] = make_int2(r, __float_as_int(dv));
        edata[r] = make_int2(d, __float_as_int(dv * dv));  // self-loop at slot 0
    }
    if (b == gridDim.x - 1 && tid == 255) rd2[N] = make_int2(blockOff + ssum[255], 0);
}

// fill: direct scatter, no atomics, no LDS.
// slot = row_start[d] + 1 + chunkpfx[c][d] + lrank[i],  c = i/ech.
__global__ __launch_bounds__(256) void GCN_fill_k(const int* __restrict__ edge,
                                                  const int* __restrict__ lrank,
                                                  const int* __restrict__ chunkhist,
                                                  const int2* __restrict__ rd2,
                                                  int2* __restrict__ edata,
                                                  int N, int E, int ech) {
    int i = blockIdx.x * 256 + threadIdx.x;
    if (i >= E) return;
    int s = edge[i];
    int d = edge[E + i];
    int lr = lrank[i];
    int c = i / ech;
    int2 rdd = rd2[d];
    float ds = __int_as_float(rd2[s].y);
    int slot = rdd.x + 1 + chunkhist[(size_t)c * N + d] + lr;
    edata[slot] = make_int2(s, __float_as_int(ds * __int_as_float(rdd.y)));
}

// MEGA-B: agg1 (16 lanes/node, x4 unroll) -> h rows in LDS -> gemm2 fused.
// h2 written as bf16 (ushort), 32B/row.
__global__ __launch_bounds__(256) void GCN_agg1gemm2_k(
        const ushort* __restrict__ h1, const int2* __restrict__ rd2,
        const int2* __restrict__ ed, const float* __restrict__ b1,
        const float* __restrict__ W2, ushort* __restrict__ h2b, int N) {
    __shared__ float w2s[FH][FO];        // 8 KiB
    __shared__ float hs[16][FH + 4];     // 8.25 KiB
    int tid = threadIdx.x;
    #pragma unroll
    for (int j = 0; j < (FH * FO) / 256; j++) {
        int i = tid + j * 256;
        w2s[i >> 4][i & 15] = W2[i];
    }

    int node0 = blockIdx.x * 16;
    int local = tid >> 4;
    int j = tid & 15;             // 16B unit: cols 8j..8j+7
    int node = node0 + local;

    if (node < N) {
        int beg = rd2[node].x, end = rd2[node + 1].x;
        const uint4* hp = (const uint4*)h1;

        float a[8];
        #pragma unroll
        for (int t = 0; t < 8; t++) a[t] = 0.f;

        int i = beg;
        for (; i + 4 <= end; i += 4) {
            int2 e0 = ed[i + 0], e1 = ed[i + 1], e2 = ed[i + 2], e3 = ed[i + 3];
            float w0 = __int_as_float(e0.y), w1 = __int_as_float(e1.y);
            float w2 = __int_as_float(e2.y), w3 = __int_as_float(e3.y);
            uint4 g0 = hp[(size_t)e0.x * 16 + j];
            uint4 g1 = hp[(size_t)e1.x * 16 + j];
            uint4 g2 = hp[(size_t)e2.x * 16 + j];
            uint4 g3 = hp[(size_t)e3.x * 16 + j];
            #pragma unroll
            for (int q = 0; q < 4; q++) {
                uint u0 = (&g0.x)[q], u1 = (&g1.x)[q], u2 = (&g2.x)[q], u3 = (&g3.x)[q];
                a[q*2+0] += __uint_as_float(u0 << 16) * w0;
                a[q*2+1] += __uint_as_float(u0 & 0xFFFF0000u) * w0;
                a[q*2+0] += __uint_as_float(u1 << 16) * w1;
                a[q*2+1] += __uint_as_float(u1 & 0xFFFF0000u) * w1;
                a[q*2+0] += __uint_as_float(u2 << 16) * w2;
                a[q*2+1] += __uint_as_float(u2 & 0xFFFF0000u) * w2;
                a[q*2+0] += __uint_as_float(u3 << 16) * w3;
                a[q*2+1] += __uint_as_float(u3 & 0xFFFF0000u) * w3;
            }
        }
        for (; i < end; i++) {
            int2 e = ed[i];
            float w = __int_as_float(e.y);
            uint4 g = hp[(size_t)e.x * 16 + j];
            #pragma unroll
            for (int q = 0; q < 4; q++) {
                uint u = (&g.x)[q];
                a[q*2+0] += __uint_as_float(u << 16) * w;
                a[q*2+1] += __uint_as_float(u & 0xFFFF0000u) * w;
            }
        }

        const float4* bp = (const float4*)b1;
        float4 bb0 = bp[j * 2 + 0];
        float4 bb1 = bp[j * 2 + 1];
        float4 o0, o1;
        o0.x = fmaxf(a[0] + bb0.x, 0.f);
        o0.y = fmaxf(a[1] + bb0.y, 0.f);
        o0.z = fmaxf(a[2] + bb0.z, 0.f);
        o0.w = fmaxf(a[3] + bb0.w, 0.f);
        o1.x = fmaxf(a[4] + bb1.x, 0.f);
        o1.y = fmaxf(a[5] + bb1.y, 0.f);
        o1.z = fmaxf(a[6] + bb1.z, 0.f);
        o1.w = fmaxf(a[7] + bb1.w, 0.f);
        *(float4*)&hs[local][j * 8 + 0] = o0;
        *(float4*)&hs[local][j * 8 + 4] = o1;
    }
    __syncthreads();

    float acc = 0.f;
    #pragma unroll 8
    for (int k = 0; k < FH; k++) acc += hs[local][k] * w2s[k][j];
    if (node < N) h2b[(size_t)node * FO + j] = f2bf(acc);
}

// AGG2 (bf16 h2) + bias + log_softmax. 8 lanes/node, 2 cols/lane, x4 unroll.
__global__ __launch_bounds__(256) void GCN_agg2_k(const ushort* __restrict__ h2b,
                                                  const int2* __restrict__ rd2,
                                                  const int2* __restrict__ ed,
                                                  const float* __restrict__ b2,
                                                  float* __restrict__ out, int N) {
    int tid = threadIdx.x;
    int node = blockIdx.x * 32 + (tid >> 3);
    if (node >= N) return;
    int f2 = tid & 7;                        // cols 2*f2, 2*f2+1
    int beg = rd2[node].x, end = rd2[node + 1].x;
    const uint* hp = (const uint*)h2b;       // row = 8 uints (16 bf16)
    float a0 = 0.f, a1 = 0.f;
    int i = beg;
    for (; i + 4 <= end; i += 4) {
        int2 e0 = ed[i + 0], e1 = ed[i + 1], e2 = ed[i + 2], e3 = ed[i + 3];
        uint u0 = hp[(size_t)e0.x * 8 + f2];
        uint u1 = hp[(size_t)e1.x * 8 + f2];
        uint u2 = hp[(size_t)e2.x * 8 + f2];
        uint u3 = hp[(size_t)e3.x * 8 + f2];
        float w0 = __int_as_float(e0.y), w1 = __int_as_float(e1.y);
        float w2 = __int_as_float(e2.y), w3 = __int_as_float(e3.y);
        a0 += __uint_as_float(u0 << 16) * w0 + __uint_as_float(u1 << 16) * w1
            + __uint_as_float(u2 << 16) * w2 + __uint_as_float(u3 << 16) * w3;
        a1 += __uint_as_float(u0 & 0xFFFF0000u) * w0 + __uint_as_float(u1 & 0xFFFF0000u) * w1
            + __uint_as_float(u2 & 0xFFFF0000u) * w2 + __uint_as_float(u3 & 0xFFFF0000u) * w3;
    }
    for (; i < end; i++) {
        int2 e = ed[i];
        uint u = hp[(size_t)e.x * 8 + f2];
        float w = __int_as_float(e.y);
        a0 += __uint_as_float(u << 16) * w;
        a1 += __uint_as_float(u & 0xFFFF0000u) * w;
    }
    float2 bb = ((const float2*)b2)[f2];
    float v0 = a0 + bb.x;
    float v1 = a1 + bb.y;
    float mx = fmaxf(v0, v1);
    #pragma unroll
    for (int m = 4; m >= 1; m >>= 1) mx = fmaxf(mx, __shfl_xor(mx, m, 8));
    float s = expf(v0 - mx) + expf(v1 - mx);
    #pragma unroll
    for (int m = 4; m >= 1; m >>= 1) s += __shfl_xor(s, m, 8);
    float ls = logf(s);
    float2 o = make_float2(v0 - mx - ls, v1 - mx - ls);
    ((float2*)out)[(size_t)node * 8 + f2] = o;
}

extern "C" void kernel_launch(void* const* d_in, const int* in_sizes, int n_in,
                              void* d_out, int out_size, void* d_ws, size_t ws_size,
                              hipStream_t stream) {
    (void)n_in; (void)out_size; (void)ws_size;
    const float* x  = (const float*)d_in[0];
    const int*   edp = (const int*)d_in[1];
    const float* W1 = (const float*)d_in[2];
    const float* b1 = (const float*)d_in[3];
    const float* W2 = (const float*)d_in[4];
    const float* b2 = (const float*)d_in[5];
    float* out = (float*)d_out;

    int N = in_sizes[0] / FIN;   // 50000
    int E = in_sizes[1] / 2;     // 800000
    int M = E + N;
    int nScanBlocks = (N + 255) / 256;               // 196 (1 node/thread)
    int nRange = (N + QPR_MAX - 1) / QPR_MAX;        // 8
    int qpr = (N + nRange - 1) / nRange;             // 6250 (<= QPR_MAX)
    int ech = (E + NCHUNK - 1) / NCHUNK;             // 6250

    char* p = (char*)d_ws;
    auto take = [&](size_t bytes) -> char* {
        char* r = p;
        p += (bytes + 255) & ~(size_t)255;
        return r;
    };
    int*    count     = (int*)take((size_t)N * 4);
    int*    lrank     = (int*)take((size_t)E * 4);
    int*    chunkhist = (int*)take((size_t)NCHUNK * N * 4);   // 25.6 MB
    int2*   rd2       = (int2*)take((size_t)(N + 1) * 8);
    int*    bsum      = (int*)take((size_t)nScanBlocks * 4);
    int2*   edata     = (int2*)take((size_t)M * 8);
    ushort* whT       = (ushort*)take((size_t)FH * FIN * 2);
    ushort* wlT       = (ushort*)take((size_t)FH * FIN * 2);
    ushort* h1        = (ushort*)take((size_t)N * FH * 2);
    ushort* h2b       = (ushort*)take((size_t)N * FO * 2);

    int nGemm  = (N + G1_BR - 1) / G1_BR;    // 782
    int nHrank = NCHUNK * nRange;            // 1024
    int eBlocks = (E + 255) / 256;           // 3125

    GCN_wprep_k<<<(FIN * FH) / 256, 256, 0, stream>>>(W1, whT, wlT);
    GCN_hrankgemm_k<<<nHrank + nGemm, 256, 0, stream>>>(
        x, whT, wlT, h1, edp, chunkhist, lrank, N, E, nHrank, nRange, qpr, ech);
    GCN_chpfxbsum_k<<<nScanBlocks, 256, 0, stream>>>(chunkhist, count, bsum, N);
    GCN_scan2_k<<<nScanBlocks, 256, 0, stream>>>(count, bsum, rd2, edata, N);
    GCN_fill_k<<<eBlocks, 256, 0, stream>>>(edp, lrank, chunkhist, rd2, edata, N, E, ech);
    GCN_agg1gemm2_k<<<(N + 15) / 16, 256, 0, stream>>>(h1, rd2, edata, b1, W2, h2b, N);
    GCN_agg2_k<<<(N + 31) / 32, 256, 0, stream>>>(h2b, rd2, edata, b2, out, N);
}

// Round 16
// 120.624 us; speedup vs baseline: 1.4794x; 1.1426x over previous
//
#include <hip/hip_runtime.h>
#include <hip/hip_bf16.h>
#include <math.h>

// ---------------------------------------------------------------------------
// GCN 2-layer forward. Pipeline (7 dispatches):
//   1) zerowprep: count8[8][N]=0  ||  W1^T -> bf16 hi/lo split
//   2) histgemm: GEMM1 (MFMA, 3-pass split bf16) || hist8 (copy = blk%8,
//      rank[i] = atomicAdd(count8[c][dst],1)) -- 8-way replicated counters
//      spread contention across XCD L2s
//   3) chpfxbsum: count8 -> in-place per-copy exclusive prefix; count[d]; bsum
//   4) scan2 -> rd2 = {row_start, dinv}; seeds self-loop edata
//   5) fill: direct scatter edata[rs[d]+1+copypfx[c][d]+rank[i]], c=(i>>8)&7
//   6) MEGA-B: agg1 (gather+bias+relu) -> h in LDS -> gemm2 -> h2 (bf16)
//   7) AGG2 (bf16 h2, 8 lanes/node) + bias + log_softmax fused
// ---------------------------------------------------------------------------

#define FIN 256
#define FH  128
#define FO  16
#define NCOPY 8

typedef unsigned int uint;
typedef unsigned short ushort;
typedef __attribute__((ext_vector_type(8))) short bf16x8;
typedef __attribute__((ext_vector_type(4))) float f32x4;

static __device__ __forceinline__ ushort f2bf(float f) {
    __hip_bfloat16 b = __float2bfloat16(f);
    return *reinterpret_cast<ushort*>(&b);
}
static __device__ __forceinline__ float bf2f(ushort u) {
    return __uint_as_float(((uint)u) << 16);
}

// blocks [0,nZero): zero count8; blocks [nZero, nZero+128): W1 hi/lo split.
__global__ __launch_bounds__(256) void GCN_zerowprep_k(int* __restrict__ count8,
                                                       int total8,
                                                       const float* __restrict__ W1,
                                                       ushort* __restrict__ whT,
                                                       ushort* __restrict__ wlT,
                                                       int nZero) {
    if ((int)blockIdx.x < nZero) {
        int i = blockIdx.x * 256 + threadIdx.x;
        if (i < total8) count8[i] = 0;
    } else {
        int i = (blockIdx.x - nZero) * 256 + threadIdx.x;   // < 32768
        int k = i >> 7, c = i & 127;
        float w = W1[i];
        ushort hh = f2bf(w);
        ushort hl = f2bf(w - bf2f(hh));
        whT[c * 256 + k] = hh;
        wlT[c * 256 + k] = hl;
    }
}

// GEMM1 tile params
#define G1_BR 64
#define G1_KC 32

// blocks [0,nGemm): GEMM1; blocks [nGemm, nGemm+eBlocks): hist8.
// hist8: edge block b (256 edges) adds to counter copy b%8; rank = return.
__global__ __launch_bounds__(256, 4) void GCN_histgemm_k(
        const float* __restrict__ x, const ushort* __restrict__ whT,
        const ushort* __restrict__ wlT, ushort* __restrict__ h1,
        const int* __restrict__ edge, int* __restrict__ count8,
        int* __restrict__ rank, int N, int E, int nGemm) {
    __shared__ __align__(16) ushort xh_s[G1_BR * G1_KC];   // 4 KiB
    __shared__ __align__(16) ushort xl_s[G1_BR * G1_KC];   // 4 KiB
    __shared__ __align__(16) ushort wh_s[FH * G1_KC];      // 8 KiB
    __shared__ __align__(16) ushort wl_s[FH * G1_KC];      // 8 KiB
    int tid = threadIdx.x;

    if ((int)blockIdx.x >= nGemm) {
        // ---- hist8 path ----
        int b = blockIdx.x - nGemm;
        int i = b * 256 + tid;
        if (i < E) {
            int c = b & (NCOPY - 1);
            rank[i] = atomicAdd(&count8[(size_t)c * N + edge[E + i]], 1);
        }
        return;
    }

    // ---- gemm1 path ----
    int row0 = blockIdx.x * G1_BR;
    int ln = tid & 63;
    int w  = tid >> 6;          // wave 0..3 -> col slab w*32
    int ln15 = ln & 15;
    int q16  = ln >> 4;         // k-slot 0..3

    f32x4 acc[4][2];
    #pragma unroll
    for (int mr = 0; mr < 4; mr++)
        #pragma unroll
        for (int nc = 0; nc < 2; nc++) acc[mr][nc] = (f32x4){0.f, 0.f, 0.f, 0.f};

    for (int kc = 0; kc < FIN; kc += G1_KC) {
        #pragma unroll
        for (int j = 0; j < 2; j++) {
            int u = tid + j * 256;
            int r = u >> 3, kq = u & 7;       // 8 float4 per row
            int gr = row0 + r;
            float4 v = make_float4(0.f, 0.f, 0.f, 0.f);
            if (gr < N) v = *(const float4*)&x[(size_t)gr * FIN + kc + kq * 4];
            ushort h0 = f2bf(v.x), h1v = f2bf(v.y), h2 = f2bf(v.z), h3 = f2bf(v.w);
            ushort l0 = f2bf(v.x - bf2f(h0));
            ushort l1 = f2bf(v.y - bf2f(h1v));
            ushort l2 = f2bf(v.z - bf2f(h2));
            ushort l3 = f2bf(v.w - bf2f(h3));
            uint2 hw, lw;
            hw.x = (uint)h0 | ((uint)h1v << 16);
            hw.y = (uint)h2 | ((uint)h3 << 16);
            lw.x = (uint)l0 | ((uint)l1 << 16);
            lw.y = (uint)l2 | ((uint)l3 << 16);
            int byte = (r * 64 + kq * 8) ^ (((r >> 1) & 3) << 4);
            *(uint2*)((char*)xh_s + byte) = hw;
            *(uint2*)((char*)xl_s + byte) = lw;
        }
        #pragma unroll
        for (int j = 0; j < 2; j++) {
            int u = tid + j * 256;
            int c = u >> 2, ku = u & 3;       // 4 x 16B per col
            uint4 vh = *(const uint4*)&whT[(size_t)c * 256 + kc + ku * 8];
            uint4 vl = *(const uint4*)&wlT[(size_t)c * 256 + kc + ku * 8];
            int byte = (c * 64 + ku * 16) ^ (((c >> 1) & 3) << 4);
            *(uint4*)((char*)wh_s + byte) = vh;
            *(uint4*)((char*)wl_s + byte) = vl;
        }
        __syncthreads();

        bf16x8 ah[4], al[4], bh[2], bl[2];
        #pragma unroll
        for (int mr = 0; mr < 4; mr++) {
            int r = mr * 16 + ln15;
            int byte = r * 64 + ((q16 * 16) ^ (((r >> 1) & 3) << 4));
            ah[mr] = *(const bf16x8*)((const char*)xh_s + byte);
            al[mr] = *(const bf16x8*)((const char*)xl_s + byte);
        }
        #pragma unroll
        for (int nc = 0; nc < 2; nc++) {
            int c = w * 32 + nc * 16 + ln15;
            int byte = c * 64 + ((q16 * 16) ^ (((c >> 1) & 3) << 4));
            bh[nc] = *(const bf16x8*)((const char*)wh_s + byte);
            bl[nc] = *(const bf16x8*)((const char*)wl_s + byte);
        }
        #pragma unroll
        for (int mr = 0; mr < 4; mr++)
            #pragma unroll
            for (int nc = 0; nc < 2; nc++) {
                acc[mr][nc] = __builtin_amdgcn_mfma_f32_16x16x32_bf16(
                    ah[mr], bh[nc], acc[mr][nc], 0, 0, 0);
                acc[mr][nc] = __builtin_amdgcn_mfma_f32_16x16x32_bf16(
                    al[mr], bh[nc], acc[mr][nc], 0, 0, 0);
                acc[mr][nc] = __builtin_amdgcn_mfma_f32_16x16x32_bf16(
                    ah[mr], bl[nc], acc[mr][nc], 0, 0, 0);
            }
        __syncthreads();
    }

    // epilogue: D layout col=lane&15, row=(lane>>4)*4+reg  [m89-verified]
    #pragma unroll
    for (int mr = 0; mr < 4; mr++) {
        #pragma unroll
        for (int nc = 0; nc < 2; nc++) {
            int cw = w * 32 + nc * 16 + ln15;
            #pragma unroll
            for (int j = 0; j < 4; j++) {
                int gr = row0 + mr * 16 + q16 * 4 + j;
                if (gr < N) h1[(size_t)gr * FH + cw] = f2bf(acc[mr][nc][j]);
            }
        }
    }
}

// chpfxbsum: 1 node/thread. count8[c][d] -> exclusive prefix over c;
// count[d] = total; bsum[blk] = sum(count+1) over the block's 256 nodes.
__global__ __launch_bounds__(256) void GCN_chpfxbsum_k(int* __restrict__ count8,
                                                       int* __restrict__ count,
                                                       int* __restrict__ bsum,
                                                       int N) {
    int tid = threadIdx.x;
    int d = blockIdx.x * 256 + tid;
    int local = 0;
    if (d < N) {
        int run = 0;
        #pragma unroll
        for (int c = 0; c < NCOPY; c++) {
            int* p = &count8[(size_t)c * N + d];
            int v = *p; *p = run; run += v;
        }
        count[d] = run;
        local = run + 1;
    }
    __shared__ int red[256];
    red[tid] = local;
    __syncthreads();
    for (int st = 128; st > 0; st >>= 1) {
        if (tid < st) red[tid] += red[tid + st];
        __syncthreads();
    }
    if (tid == 0) bsum[blockIdx.x] = red[0];
}

// scan2: 1 node/thread. rd2[v] = {row_start[v], bits(dinv[v])}; rd2[N].x =
// total; seeds self-loop entry edata[row_start[v]] = {v, dinv^2}.
__global__ __launch_bounds__(256) void GCN_scan2_k(const int* __restrict__ count,
                                                   const int* __restrict__ bsum,
                                                   int2* __restrict__ rd2,
                                                   int2* __restrict__ edata, int N) {
    int tid = threadIdx.x;
    int b = blockIdx.x;
    int d = b * 256 + tid;
    int cnt1 = (d < N) ? count[d] + 1 : 0;

    __shared__ int red[256];
    int offp = 0;
    for (int t = tid; t < b; t += 256) offp += bsum[t];
    red[tid] = offp;
    __syncthreads();
    for (int st = 128; st > 0; st >>= 1) {
        if (tid < st) red[tid] += red[tid + st];
        __syncthreads();
    }
    int blockOff = red[0];
    __syncthreads();

    __shared__ int ssum[256];
    ssum[tid] = cnt1;
    __syncthreads();
    for (int off = 1; off < 256; off <<= 1) {
        int t = (tid >= off) ? ssum[tid - off] : 0;
        __syncthreads();
        ssum[tid] += t;
        __syncthreads();
    }
    int r = blockOff + ssum[tid] - cnt1;   // exclusive

    if (d < N) {
        float dv = rsqrtf((float)cnt1);
        rd2[d] = make_int2(r, __float_as_int(dv));
        edata[r] = make_int2(d, __float_as_int(dv * dv));  // self-loop at slot 0
    }
    if (b == gridDim.x - 1 && tid == 255) rd2[N] = make_int2(blockOff + ssum[255], 0);
}

// fill: direct scatter, no atomics, no LDS.
// slot = row_start[d] + 1 + copypfx[c][d] + rank[i],  c = (i>>8)&7.
__global__ __launch_bounds__(256) void GCN_fill_k(const int* __restrict__ edge,
                                                  const int* __restrict__ rank,
                                                  const int* __restrict__ count8,
                                                  const int2* __restrict__ rd2,
                                                  int2* __restrict__ edata,
                                                  int N, int E) {
    int i = blockIdx.x * 256 + threadIdx.x;
    if (i >= E) return;
    int s = edge[i];
    int d = edge[E + i];
    int rk = rank[i];
    int c = (i >> 8) & (NCOPY - 1);
    int2 rdd = rd2[d];
    float ds = __int_as_float(rd2[s].y);
    int slot = rdd.x + 1 + count8[(size_t)c * N + d] + rk;
    edata[slot] = make_int2(s, __float_as_int(ds * __int_as_float(rdd.y)));
}

// MEGA-B: agg1 (16 lanes/node, x4 unroll) -> h rows in LDS -> gemm2 fused.
// h2 written as bf16 (ushort), 32B/row.
__global__ __launch_bounds__(256) void GCN_agg1gemm2_k(
        const ushort* __restrict__ h1, const int2* __restrict__ rd2,
        const int2* __restrict__ ed, const float* __restrict__ b1,
        const float* __restrict__ W2, ushort* __restrict__ h2b, int N) {
    __shared__ float w2s[FH][FO];        // 8 KiB
    __shared__ float hs[16][FH + 4];     // 8.25 KiB
    int tid = threadIdx.x;
    #pragma unroll
    for (int j = 0; j < (FH * FO) / 256; j++) {
        int i = tid + j * 256;
        w2s[i >> 4][i & 15] = W2[i];
    }

    int node0 = blockIdx.x * 16;
    int local = tid >> 4;
    int j = tid & 15;             // 16B unit: cols 8j..8j+7
    int node = node0 + local;

    if (node < N) {
        int beg = rd2[node].x, end = rd2[node + 1].x;
        const uint4* hp = (const uint4*)h1;

        float a[8];
        #pragma unroll
        for (int t = 0; t < 8; t++) a[t] = 0.f;

        int i = beg;
        for (; i + 4 <= end; i += 4) {
            int2 e0 = ed[i + 0], e1 = ed[i + 1], e2 = ed[i + 2], e3 = ed[i + 3];
            float w0 = __int_as_float(e0.y), w1 = __int_as_float(e1.y);
            float w2 = __int_as_float(e2.y), w3 = __int_as_float(e3.y);
            uint4 g0 = hp[(size_t)e0.x * 16 + j];
            uint4 g1 = hp[(size_t)e1.x * 16 + j];
            uint4 g2 = hp[(size_t)e2.x * 16 + j];
            uint4 g3 = hp[(size_t)e3.x * 16 + j];
            #pragma unroll
            for (int q = 0; q < 4; q++) {
                uint u0 = (&g0.x)[q], u1 = (&g1.x)[q], u2 = (&g2.x)[q], u3 = (&g3.x)[q];
                a[q*2+0] += __uint_as_float(u0 << 16) * w0;
                a[q*2+1] += __uint_as_float(u0 & 0xFFFF0000u) * w0;
                a[q*2+0] += __uint_as_float(u1 << 16) * w1;
                a[q*2+1] += __uint_as_float(u1 & 0xFFFF0000u) * w1;
                a[q*2+0] += __uint_as_float(u2 << 16) * w2;
                a[q*2+1] += __uint_as_float(u2 & 0xFFFF0000u) * w2;
                a[q*2+0] += __uint_as_float(u3 << 16) * w3;
                a[q*2+1] += __uint_as_float(u3 & 0xFFFF0000u) * w3;
            }
        }
        for (; i < end; i++) {
            int2 e = ed[i];
            float w = __int_as_float(e.y);
            uint4 g = hp[(size_t)e.x * 16 + j];
            #pragma unroll
            for (int q = 0; q < 4; q++) {
                uint u = (&g.x)[q];
                a[q*2+0] += __uint_as_float(u << 16) * w;
                a[q*2+1] += __uint_as_float(u & 0xFFFF0000u) * w;
            }
        }

        const float4* bp = (const float4*)b1;
        float4 bb0 = bp[j * 2 + 0];
        float4 bb1 = bp[j * 2 + 1];
        float4 o0, o1;
        o0.x = fmaxf(a[0] + bb0.x, 0.f);
        o0.y = fmaxf(a[1] + bb0.y, 0.f);
        o0.z = fmaxf(a[2] + bb0.z, 0.f);
        o0.w = fmaxf(a[3] + bb0.w, 0.f);
        o1.x = fmaxf(a[4] + bb1.x, 0.f);
        o1.y = fmaxf(a[5] + bb1.y, 0.f);
        o1.z = fmaxf(a[6] + bb1.z, 0.f);
        o1.w = fmaxf(a[7] + bb1.w, 0.f);
        *(float4*)&hs[local][j * 8 + 0] = o0;
        *(float4*)&hs[local][j * 8 + 4] = o1;
    }
    __syncthreads();

    float acc = 0.f;
    #pragma unroll 8
    for (int k = 0; k < FH; k++) acc += hs[local][k] * w2s[k][j];
    if (node < N) h2b[(size_t)node * FO + j] = f2bf(acc);
}

// AGG2 (bf16 h2) + bias + log_softmax. 8 lanes/node, 2 cols/lane, x4 unroll.
__global__ __launch_bounds__(256) void GCN_agg2_k(const ushort* __restrict__ h2b,
                                                  const int2* __restrict__ rd2,
                                                  const int2* __restrict__ ed,
                                                  const float* __restrict__ b2,
                                                  float* __restrict__ out, int N) {
    int tid = threadIdx.x;
    int node = blockIdx.x * 32 + (tid >> 3);
    if (node >= N) return;
    int f2 = tid & 7;                        // cols 2*f2, 2*f2+1
    int beg = rd2[node].x, end = rd2[node + 1].x;
    const uint* hp = (const uint*)h2b;       // row = 8 uints (16 bf16)
    float a0 = 0.f, a1 = 0.f;
    int i = beg;
    for (; i + 4 <= end; i += 4) {
        int2 e0 = ed[i + 0], e1 = ed[i + 1], e2 = ed[i + 2], e3 = ed[i + 3];
        uint u0 = hp[(size_t)e0.x * 8 + f2];
        uint u1 = hp[(size_t)e1.x * 8 + f2];
        uint u2 = hp[(size_t)e2.x * 8 + f2];
        uint u3 = hp[(size_t)e3.x * 8 + f2];
        float w0 = __int_as_float(e0.y), w1 = __int_as_float(e1.y);
        float w2 = __int_as_float(e2.y), w3 = __int_as_float(e3.y);
        a0 += __uint_as_float(u0 << 16) * w0 + __uint_as_float(u1 << 16) * w1
            + __uint_as_float(u2 << 16) * w2 + __uint_as_float(u3 << 16) * w3;
        a1 += __uint_as_float(u0 & 0xFFFF0000u) * w0 + __uint_as_float(u1 & 0xFFFF0000u) * w1
            + __uint_as_float(u2 & 0xFFFF0000u) * w2 + __uint_as_float(u3 & 0xFFFF0000u) * w3;
    }
    for (; i < end; i++) {
        int2 e = ed[i];
        uint u = hp[(size_t)e.x * 8 + f2];
        float w = __int_as_float(e.y);
        a0 += __uint_as_float(u << 16) * w;
        a1 += __uint_as_float(u & 0xFFFF0000u) * w;
    }
    float2 bb = ((const float2*)b2)[f2];
    float v0 = a0 + bb.x;
    float v1 = a1 + bb.y;
    float mx = fmaxf(v0, v1);
    #pragma unroll
    for (int m = 4; m >= 1; m >>= 1) mx = fmaxf(mx, __shfl_xor(mx, m, 8));
    float s = expf(v0 - mx) + expf(v1 - mx);
    #pragma unroll
    for (int m = 4; m >= 1; m >>= 1) s += __shfl_xor(s, m, 8);
    float ls = logf(s);
    float2 o = make_float2(v0 - mx - ls, v1 - mx - ls);
    ((float2*)out)[(size_t)node * 8 + f2] = o;
}

extern "C" void kernel_launch(void* const* d_in, const int* in_sizes, int n_in,
                              void* d_out, int out_size, void* d_ws, size_t ws_size,
                              hipStream_t stream) {
    (void)n_in; (void)out_size; (void)ws_size;
    const float* x  = (const float*)d_in[0];
    const int*   edp = (const int*)d_in[1];
    const float* W1 = (const float*)d_in[2];
    const float* b1 = (const float*)d_in[3];
    const float* W2 = (const float*)d_in[4];
    const float* b2 = (const float*)d_in[5];
    float* out = (float*)d_out;

    int N = in_sizes[0] / FIN;   // 50000
    int E = in_sizes[1] / 2;     // 800000
    int M = E + N;
    int nScanBlocks = (N + 255) / 256;       // 196 (1 node/thread)

    char* p = (char*)d_ws;
    auto take = [&](size_t bytes) -> char* {
        char* r = p;
        p += (bytes + 255) & ~(size_t)255;
        return r;
    };
    int*    count  = (int*)take((size_t)N * 4);
    int*    count8 = (int*)take((size_t)NCOPY * N * 4);   // 1.6 MB
    int*    rank   = (int*)take((size_t)E * 4);
    int2*   rd2    = (int2*)take((size_t)(N + 1) * 8);
    int*    bsum   = (int*)take((size_t)nScanBlocks * 4);
    int2*   edata  = (int2*)take((size_t)M * 8);
    ushort* whT    = (ushort*)take((size_t)FH * FIN * 2);
    ushort* wlT    = (ushort*)take((size_t)FH * FIN * 2);
    ushort* h1     = (ushort*)take((size_t)N * FH * 2);
    ushort* h2b    = (ushort*)take((size_t)N * FO * 2);

    int eBlocks = (E + 255) / 256;            // 3125
    int nGemm   = (N + G1_BR - 1) / G1_BR;    // 782
    int total8  = NCOPY * N;
    int nZero   = (total8 + 255) / 256;       // 1563

    GCN_zerowprep_k<<<nZero + (FIN * FH) / 256, 256, 0, stream>>>(
        count8, total8, W1, whT, wlT, nZero);
    GCN_histgemm_k<<<nGemm + eBlocks, 256, 0, stream>>>(
        x, whT, wlT, h1, edp, count8, rank, N, E, nGemm);
    GCN_chpfxbsum_k<<<nScanBlocks, 256, 0, stream>>>(count8, count, bsum, N);
    GCN_scan2_k<<<nScanBlocks, 256, 0, stream>>>(count, bsum, rd2, edata, N);
    GCN_fill_k<<<eBlocks, 256, 0, stream>>>(edp, rank, count8, rd2, edata, N, E);
    GCN_agg1gemm2_k<<<(N + 15) / 16, 256, 0, stream>>>(h1, rd2, edata, b1, W2, h2b, N);
    GCN_agg2_k<<<(N + 31) / 32, 256, 0, stream>>>(h2b, rd2, edata, b2, out, N);
}